// Round 1
// baseline (5718.222 us; speedup 1.0000x reference)
//
#include <hip/hip_runtime.h>

#define BSZ  5
#define PROJ 1000
#define DET  513
#define IMG  362
#define NPIX (IMG * IMG)          // 131044
#define SINO (PROJ * DET)         // 513000
#define NNZ  20000000

// acc layout in workspace: [BSZ][NPIX] batch accumulators, then [NPIX] sensitivity
__global__ void bp_scatter_kernel(const float* __restrict__ sino,
                                  const float* __restrict__ vals,
                                  const int*   __restrict__ rows,
                                  const int*   __restrict__ cols,
                                  float* __restrict__ acc) {
    const long long stride = (long long)gridDim.x * blockDim.x;
    for (long long i = (long long)blockIdx.x * blockDim.x + threadIdx.x;
         i < NNZ; i += stride) {
        const float v = vals[i];
        const int   r = rows[i];
        const int   c = cols[i];
        float* accr = acc + r;
        // sensitivity
        atomicAdd(accr + (size_t)BSZ * NPIX, v);
        // per-batch back-projection
#pragma unroll
        for (int b = 0; b < BSZ; ++b) {
            atomicAdd(accr + (size_t)b * NPIX, v * sino[(size_t)b * SINO + c]);
        }
    }
}

__global__ void bp_divide_kernel(const float* __restrict__ acc,
                                 float* __restrict__ out) {
    const int i = blockIdx.x * blockDim.x + threadIdx.x;
    if (i < BSZ * NPIX) {
        const int p = i % NPIX;
        out[i] = acc[i] / acc[(size_t)BSZ * NPIX + p];
    }
}

extern "C" void kernel_launch(void* const* d_in, const int* in_sizes, int n_in,
                              void* d_out, int out_size, void* d_ws, size_t ws_size,
                              hipStream_t stream) {
    const float* sino = (const float*)d_in[0];   // [BSZ, PROJ, DET, 1] contiguous
    const float* vals = (const float*)d_in[1];   // [NNZ]
    const int*   rows = (const int*)d_in[2];     // [NNZ]
    const int*   cols = (const int*)d_in[3];     // [NNZ]
    float* out = (float*)d_out;                  // [BSZ, IMG, IMG, 1]
    float* acc = (float*)d_ws;                   // (BSZ+1)*NPIX floats

    const size_t acc_bytes = (size_t)(BSZ + 1) * NPIX * sizeof(float);
    hipMemsetAsync(acc, 0, acc_bytes, stream);

    // scatter: grid-stride over NNZ
    const int block = 256;
    const int grid = 2048;   // 256 CUs * 8 blocks/CU
    bp_scatter_kernel<<<grid, block, 0, stream>>>(sino, vals, rows, cols, acc);

    // divide + write output
    const int n_out = BSZ * NPIX;
    bp_divide_kernel<<<(n_out + block - 1) / block, block, 0, stream>>>(acc, out);
}